// Round 1
// baseline (666.912 us; speedup 1.0000x reference)
//
#include <hip/hip_runtime.h>

#define PRIOR_SCALE 0.3f
#define NEGF (-1e30f)
#define LOG2E_F 1.4426950408889634f
#define LN2_F 0.6931471805599453f

__device__ __forceinline__ float fexp2(float x) { return __builtin_amdgcn_exp2f(x); }
__device__ __forceinline__ float flog2(float x) { return __builtin_amdgcn_logf(x); }

// base-2 logsumexp of 2 / 3 terms
__device__ __forceinline__ float lse2b(float a, float b) {
  float m = fmaxf(a, b);
  float d = fminf(a, b) - m;
  return m + flog2(1.0f + fexp2(d));
}
__device__ __forceinline__ float lse3b(float a, float b, float c) {
  float m = fmaxf(fmaxf(a, b), c);  // -> v_max3_f32
  float s = fexp2(a - m) + fexp2(b - m) + fexp2(c - m);
  return m + flog2(s);
}

// ---------------- CTC forward: 1 wave per batch element ----------------
// Requires V==256 (float4/lane row staging) and S==256 (4 targets/lane, L=513=64*8+1).
extern "C" __global__ void __launch_bounds__(64)
ctc_fwd_kernel(const float* __restrict__ lp, const float* __restrict__ lpri,
               const int* __restrict__ tgt, const int* __restrict__ ilen,
               const int* __restrict__ tlen, float* __restrict__ nll,
               int T, int N, int V, int S) {
  const int n = blockIdx.x;
  const int lane = threadIdx.x;
  __shared__ __align__(16) float rowbuf[2][256];
  __shared__ float afin[513];

  const int len = ilen[n];   // loop to len-1 == reference's freeze-at-t>=len
  const int tl  = tlen[n];

  // per-lane constants: targets s = 4*lane .. 4*lane+3
  const int sBase = 4 * lane;
  const int* trow = tgt + n * S;
  const int tv1 = trow[sBase + 0];
  const int tv2 = trow[sBase + 1];
  const int tv3 = trow[sBase + 2];
  const int tv4 = trow[sBase + 3];
  const int prev = (sBase > 0) ? trow[sBase - 1] : -1;
  // skip-transition penalty: 0 if allowed, -1e30 if not (branchless 3rd LSE term)
  const float sk1 = (sBase >= 1 && tv1 != prev) ? 0.0f : NEGF;
  const float sk2 = (tv2 != tv1) ? 0.0f : NEGF;
  const float sk3 = (tv3 != tv2) ? 0.0f : NEGF;
  const float sk4 = (tv4 != tv3) ? 0.0f : NEGF;
  // prior-scale emission offsets, pre-multiplied into base-2 domain
  const float ep1  = (-PRIOR_SCALE * lpri[tv1]) * LOG2E_F;
  const float ep2  = (-PRIOR_SCALE * lpri[tv2]) * LOG2E_F;
  const float ep3  = (-PRIOR_SCALE * lpri[tv3]) * LOG2E_F;
  const float ep4  = (-PRIOR_SCALE * lpri[tv4]) * LOG2E_F;
  const float epbl = (-PRIOR_SCALE * lpri[0])   * LOG2E_F;

  const size_t rstride = (size_t)N * V;
  const float* rp = lp + (size_t)n * V;  // row t = rp + t*rstride

  // 4-slot register prefetch ring (static indices via unroll)
  float4 r0, r1, r2, r3;
#define LOADROW(DST, TT_) { int tt = (TT_); if (tt > T - 1) tt = T - 1; \
    DST = *(const float4*)(rp + (size_t)tt * rstride + 4 * lane); }
  LOADROW(r0, 0); LOADROW(r1, 1); LOADROW(r2, 2); LOADROW(r3, 3);

  // stage row 0, init alpha (base-2 domain)
  ((float4*)(rowbuf[0]))[lane] = r0;
  __syncthreads();
  float x0 = NEGF, x1 = NEGF, x2 = NEGF, x3 = NEGF, x4 = NEGF,
        x5 = NEGF, x6 = NEGF, x7 = NEGF, x8 = NEGF;
  if (lane == 0) {
    x0 = fmaf(rowbuf[0][0],   LOG2E_F, epbl);  // alpha0[0] = blank emit @t0
    x1 = fmaf(rowbuf[0][tv1], LOG2E_F, ep1);   // alpha0[1] = first label @t0
  }

  int t = 1;
  // One iteration: stage row t regs->LDS, prefetch row t+3, gather 5 emits,
  // update 9 positions. Cross-lane: only n7 = prev lane's x7 (= alpha[8l-1]).
#define CTC_ITER(SS, LS, B)                                                   \
  {                                                                           \
    ((float4*)(rowbuf[(B)]))[lane] = SS;                                      \
    LOADROW(LS, t + 3);                                                       \
    float gb = rowbuf[(B)][0];                                                \
    float g1 = rowbuf[(B)][tv1];                                              \
    float g2 = rowbuf[(B)][tv2];                                              \
    float g3 = rowbuf[(B)][tv3];                                              \
    float g4 = rowbuf[(B)][tv4];                                              \
    float eb = fmaf(gb, LOG2E_F, epbl);                                       \
    float e1 = fmaf(g1, LOG2E_F, ep1);                                        \
    float e2 = fmaf(g2, LOG2E_F, ep2);                                        \
    float e3 = fmaf(g3, LOG2E_F, ep3);                                        \
    float e4 = fmaf(g4, LOG2E_F, ep4);                                        \
    float n7 = __shfl_up(x7, 1);                                              \
    n7 = (lane == 0) ? NEGF : n7;                                             \
    float y0 = lse2b(x0, n7) + eb;                                            \
    float y1 = lse3b(x1, x0, n7 + sk1) + e1;                                  \
    float y2 = lse2b(x2, x1) + eb;                                            \
    float y3 = lse3b(x3, x2, x1 + sk2) + e2;                                  \
    float y4 = lse2b(x4, x3) + eb;                                            \
    float y5 = lse3b(x5, x4, x3 + sk3) + e3;                                  \
    float y6 = lse2b(x6, x5) + eb;                                            \
    float y7 = lse3b(x7, x6, x5 + sk4) + e4;                                  \
    float y8 = lse2b(x8, x7) + eb;                                            \
    x0 = y0; x1 = y1; x2 = y2; x3 = y3; x4 = y4;                              \
    x5 = y5; x6 = y6; x7 = y7; x8 = y8;                                       \
    ++t;                                                                      \
  }

  while (t < len) {
    if (t < len) CTC_ITER(r1, r0, 1)   // t % 4 == 1
    if (t < len) CTC_ITER(r2, r1, 0)   // t % 4 == 2
    if (t < len) CTC_ITER(r3, r2, 1)   // t % 4 == 3
    if (t < len) CTC_ITER(r0, r3, 0)   // t % 4 == 0
  }
#undef CTC_ITER
#undef LOADROW

  // final: ll = logaddexp(alpha[2*tl], alpha[2*tl-1]) in natural log
  afin[8 * lane + 0] = x0; afin[8 * lane + 1] = x1;
  afin[8 * lane + 2] = x2; afin[8 * lane + 3] = x3;
  afin[8 * lane + 4] = x4; afin[8 * lane + 5] = x5;
  afin[8 * lane + 6] = x6; afin[8 * lane + 7] = x7;
  if (lane == 63) afin[512] = x8;
  __syncthreads();
  if (lane == 0) {
    const int i1 = 2 * tl;
    float ll = lse2b(afin[i1], afin[i1 - 1]) * LN2_F;
    nll[n] = -ll / (float)tl;
  }
}

// ---------------- prior pass: sum of exp over valid frames, per vocab ----------------
extern "C" __global__ void __launch_bounds__(256)
prior_sum_kernel(const float* __restrict__ lp, const int* __restrict__ ilen,
                 float* __restrict__ acc, int T, int N, int V) {
  const int v = threadIdx.x;   // blockDim.x == V
  const int t = blockIdx.x;    // gridDim.x == T
  float s = 0.0f;
  const float* base = lp + (size_t)t * N * V + v;
  for (int n = 0; n < N; ++n) {
    if (t < ilen[n]) s += __expf(base[(size_t)n * V]);
  }
  atomicAdd(&acc[v], s);
}

extern "C" __global__ void zero_acc_kernel(float* acc, int V) {
  if ((int)threadIdx.x < V) acc[threadIdx.x] = 0.0f;
}

extern "C" __global__ void finalize_kernel(const float* __restrict__ acc,
                                           const float* __restrict__ nll,
                                           float* __restrict__ out, int N, int V) {
  const int i = threadIdx.x;
  if (i < V) out[1 + i] = __logf(acc[i]);
  if (i == 0) {
    float s = 0.0f;
    for (int n = 0; n < N; ++n) s += nll[n];
    out[0] = s / (float)N;
  }
}

extern "C" void kernel_launch(void* const* d_in, const int* in_sizes, int n_in,
                              void* d_out, int out_size, void* d_ws, size_t ws_size,
                              hipStream_t stream) {
  const float* lp   = (const float*)d_in[0];  // [T,N,V] fp32
  const float* lpri = (const float*)d_in[1];  // [1,V]   fp32
  const int*   tgt  = (const int*)d_in[2];    // [N,S]
  const int*   ilen = (const int*)d_in[3];    // [N]
  const int*   tlen = (const int*)d_in[4];    // [N]
  const int V = in_sizes[1];
  const int N = in_sizes[3];
  const int S = in_sizes[2] / N;
  const int T = in_sizes[0] / (N * V);

  float* out = (float*)d_out;          // [0]=loss, [1..V]=prior logsumexp
  float* acc = (float*)d_ws;           // [V] exp-sum accumulators
  float* nll = acc + V;                // [N] per-utterance -ll/tl

  zero_acc_kernel<<<1, 256, 0, stream>>>(acc, V);
  prior_sum_kernel<<<T, V, 0, stream>>>(lp, ilen, acc, T, N, V);
  ctc_fwd_kernel<<<N, 64, 0, stream>>>(lp, lpri, tgt, ilen, tlen, nll, T, N, V, S);
  finalize_kernel<<<1, 256, 0, stream>>>(acc, nll, out, N, V);
}

// Round 2
// 605.704 us; speedup vs baseline: 1.1011x; 1.1011x over previous
//
#include <hip/hip_runtime.h>

#define PRIOR_SCALE 0.3f
#define NEGF (-1e30f)
#define LOG2E_F 1.4426950408889634f
#define LN2_F 0.6931471805599453f

__device__ __forceinline__ float fexp2(float x) { return __builtin_amdgcn_exp2f(x); }
__device__ __forceinline__ float flog2(float x) { return __builtin_amdgcn_logf(x); }

// base-2 logsumexp
__device__ __forceinline__ float lse2b(float a, float b) {
  float m = fmaxf(a, b);
  float d = fminf(a, b) - m;
  return m + flog2(1.0f + fexp2(d));
}
// 3-term, med3 trick: max term's exp2 is exactly 1 -> only 2 exp + 1 log
__device__ __forceinline__ float lse3b(float a, float b, float c) {
  float mx = fmaxf(fmaxf(a, b), c);                       // v_max3
  float mn = fminf(fminf(a, b), c);                       // v_min3
  float md = fmaxf(fminf(a, b), fminf(fmaxf(a, b), c));   // v_med3
  float s = 1.0f + fexp2(md - mx) + fexp2(mn - mx);
  return mx + flog2(s);
}

// Fused kernel: blocks [0,N) run the CTC forward recursion (4 waves, 2 label
// positions per thread); blocks [N, N+pblocks) stream the label-prior
// partial sums on the otherwise-idle CUs (they overlap the serial CTC scan).
extern "C" __global__ void __launch_bounds__(256)
ctc_fused_kernel(const float* __restrict__ lp, const float* __restrict__ lpri,
                 const int* __restrict__ tgt, const int* __restrict__ ilen,
                 const int* __restrict__ tlen, float* __restrict__ nll,
                 float* __restrict__ partial, int pblocks,
                 int T, int N, int V, int S) {
  if ((int)blockIdx.x >= N) {
    // ---------------- prior partial-sum path (no LDS, no barriers) --------
    const int pb = blockIdx.x - N;
    const int v = threadIdx.x;  // V == 256 == blockDim.x
    float s = 0.0f;
    for (int t = pb; t < T; t += pblocks) {
      const float* base = lp + (size_t)t * N * V + v;
      for (int n = 0; n < N; ++n) {
        float x = base[(size_t)n * V];
        s += (t < ilen[n]) ? __expf(x) : 0.0f;
      }
    }
    partial[(size_t)pb * V + v] = s;
    return;
  }

  // ---------------- CTC forward path ------------------------------------
  const int n = blockIdx.x;
  const int g = threadIdx.x;      // 0..255 ; owns positions 2g (blank), 2g+1 (label g)
  const int lane = g & 63;
  const int wid = g >> 6;
  __shared__ __align__(16) float rowbuf[10][256];  // 10-slot ring, depth-8 prefetch
  __shared__ float bnd[2][4];                      // cross-wave boundary alpha
  __shared__ float afin[513];

  const int len = __builtin_amdgcn_readfirstlane(ilen[n]);
  const int tl = tlen[n];

  const int* trow = tgt + n * S;
  const int tv = trow[g];                       // label for position 2g+1 (s = g)
  const int tvp = (g > 0) ? trow[g - 1] : -1;
  const float sk = (g > 0 && tv != tvp) ? 0.0f : NEGF;  // skip-transition penalty
  const float ep1 = (-PRIOR_SCALE * lpri[tv]) * LOG2E_F;
  const float epb = (-PRIOR_SCALE * lpri[0]) * LOG2E_F;
  const int widm1 = wid ? wid - 1 : 0;

  const size_t rstride = (size_t)N * V;
  const float* rp = lp + (size_t)n * V;

  // prologue: wave 0 issues rows 0..8 into slots 0..8 (9 in flight)
  if (wid == 0) {
#pragma unroll
    for (int r = 0; r < 9; ++r) {
      int rr = (r < T) ? r : (T - 1);
      __builtin_amdgcn_global_load_lds(
          (const __attribute__((address_space(1))) void*)(const void*)(rp + (size_t)rr * rstride + 4 * lane),
          (__attribute__((address_space(3))) void*)(void*)(&rowbuf[r][0]), 16, 0, 0);
    }
    asm volatile("s_waitcnt vmcnt(7)" ::: "memory");  // rows 0,1 landed
  }
  asm volatile("s_waitcnt lgkmcnt(0)\n\ts_barrier" ::: "memory");

  float x0 = NEGF, x1 = NEGF, x2 = NEGF;  // alpha[2g], alpha[2g+1], (g==255: alpha[512])
  {
    float gb = rowbuf[0][0];
    float gv = rowbuf[0][tv];
    if (g == 0) {
      x0 = fmaf(gb, LOG2E_F, epb);   // alpha0[0]
      x1 = fmaf(gv, LOG2E_F, ep1);   // alpha0[1]
    }
  }
  // prefetch emissions for t=1 (row 1 landed per vmcnt(7) above)
  float gbN = rowbuf[1][0];
  float gvN = rowbuf[1][tv];

  int t = 1;
  // Per step: issue row t+8, counted vmcnt(7) (rows <= t+1 landed), exchange
  // boundary alpha, ONE raw barrier, update 2 positions from prefetched
  // emissions, then register-prefetch next row's emissions.
#define CTC_ITER(NSLOT, PSLOT, BND)                                            \
  if (t < len) {                                                               \
    if (wid == 0) {                                                            \
      int rr = t + 8; if (rr > T - 1) rr = T - 1;                              \
      __builtin_amdgcn_global_load_lds(                                        \
          (const __attribute__((address_space(1))) void*)(const void*)(rp + (size_t)rr * rstride + 4 * lane), \
          (__attribute__((address_space(3))) void*)(void*)(&rowbuf[(PSLOT)][0]), 16, 0, 0); \
      asm volatile("s_waitcnt vmcnt(7)" ::: "memory");                         \
    }                                                                          \
    if (lane == 63) bnd[(BND)][wid] = x1;                                      \
    asm volatile("s_waitcnt lgkmcnt(0)\n\ts_barrier" ::: "memory");            \
    float eb = fmaf(gbN, LOG2E_F, epb);                                        \
    float e1 = fmaf(gvN, LOG2E_F, ep1);                                        \
    float bv = bnd[(BND)][widm1];                                              \
    float am1 = __shfl_up(x1, 1);                                              \
    if (lane == 0) am1 = wid ? bv : NEGF;                                      \
    float x1o = x1;                                                            \
    float y0 = lse2b(x0, am1) + eb;                                            \
    float y1 = lse3b(x1, x0, am1 + sk) + e1;                                   \
    x0 = y0; x1 = y1;                                                          \
    if (g == 255) x2 = lse2b(x2, x1o) + eb;   /* position 512 */               \
    gbN = rowbuf[(NSLOT)][0];                                                  \
    gvN = rowbuf[(NSLOT)][tv];                                                 \
    ++t;                                                                       \
  }

  while (t < len) {
    CTC_ITER(2, 9, 1)
    CTC_ITER(3, 0, 0)
    CTC_ITER(4, 1, 1)
    CTC_ITER(5, 2, 0)
    CTC_ITER(6, 3, 1)
    CTC_ITER(7, 4, 0)
    CTC_ITER(8, 5, 1)
    CTC_ITER(9, 6, 0)
    CTC_ITER(0, 7, 1)
    CTC_ITER(1, 8, 0)
  }
#undef CTC_ITER

  afin[2 * g] = x0;
  afin[2 * g + 1] = x1;
  if (g == 255) afin[512] = x2;
  __syncthreads();   // also drains wave 0's outstanding loads
  if (g == 0) {
    const int i1 = 2 * tl;
    float ll = lse2b(afin[i1], afin[i1 - 1]) * LN2_F;
    nll[n] = -ll / (float)tl;
  }
}

extern "C" __global__ void finalize_kernel(const float* __restrict__ partial, int pblocks,
                                           const float* __restrict__ nll,
                                           float* __restrict__ out, int N, int V) {
  const int v = threadIdx.x;  // 256 == V
  float s = 0.0f;
  for (int pb = 0; pb < pblocks; ++pb) s += partial[(size_t)pb * V + v];
  out[1 + v] = __logf(s);
  if (v == 0) {
    float acc = 0.0f;
#pragma unroll 8
    for (int i = 0; i < N; ++i) acc += nll[i];
    out[0] = acc / (float)N;
  }
}

extern "C" void kernel_launch(void* const* d_in, const int* in_sizes, int n_in,
                              void* d_out, int out_size, void* d_ws, size_t ws_size,
                              hipStream_t stream) {
  const float* lp   = (const float*)d_in[0];  // [T,N,V] fp32
  const float* lpri = (const float*)d_in[1];  // [1,V]   fp32
  const int*   tgt  = (const int*)d_in[2];    // [N,S]
  const int*   ilen = (const int*)d_in[3];    // [N]
  const int*   tlen = (const int*)d_in[4];    // [N]
  const int V = in_sizes[1];
  const int N = in_sizes[3];
  const int S = in_sizes[2] / N;
  const int T = in_sizes[0] / (N * V);

  int pblocks = 200;  // prior-sum blocks; 32 + 200 = 232 blocks, all co-resident
  size_t need = ((size_t)pblocks * V + 64) * sizeof(float);
  if (ws_size < need) {
    long avail = (long)(ws_size / sizeof(float)) - 64;
    pblocks = (int)(avail / V);
    if (pblocks < 1) pblocks = 1;
  }

  float* out = (float*)d_out;                   // [0]=loss, [1..V]=prior logsumexp
  float* partial = (float*)d_ws;                // [pblocks*V]
  float* nll = partial + (size_t)pblocks * V;   // [N]

  ctc_fused_kernel<<<N + pblocks, 256, 0, stream>>>(lp, lpri, tgt, ilen, tlen,
                                                    nll, partial, pblocks, T, N, V, S);
  finalize_kernel<<<1, 256, 0, stream>>>(partial, pblocks, nll, out, N, V);
}